// Round 2
// baseline (821.963 us; speedup 1.0000x reference)
//
#include <hip/hip_runtime.h>
#include <stdint.h>
#include <stddef.h>

typedef unsigned short u16;
typedef __bf16 bf16_t;
typedef bf16_t bf16x8 __attribute__((ext_vector_type(8)));
typedef float f32x4 __attribute__((ext_vector_type(4)));
typedef u16 u16x4 __attribute__((ext_vector_type(4)));

#define N_NODES 50000
#define N_EDGES 65536
#define D_NODE 1024
#define D_HID 1024

// GEMM geometry (256^2 8-phase template)
#define BM 256
#define BK 64
#define BUFE (BM * BK)                 // 16384 elems = 32 KiB per (A or B) buffer
#define LDS_BYTES (4 * BUFE * 2)       // 2 dbuf x (A+B) = 131072 B

// ---------------- helpers ----------------

__device__ __forceinline__ u16 f2bf(float f) {
  union { float f; uint32_t u; } v; v.f = f;
  uint32_t u = v.u;
  u += 0x7FFF + ((u >> 16) & 1);   // RNE
  return (u16)(u >> 16);
}

typedef __attribute__((address_space(1))) const void GV;
typedef __attribute__((address_space(3))) void LV;

// async global->LDS, 16B per lane; LDS dest = wave-uniform base + lane*16
__device__ __forceinline__ void gll16(const void* g, void* lds_wave_base) {
  __builtin_amdgcn_global_load_lds((GV*)g, (LV*)lds_wave_base, 16, 0, 0);
}

// ---------------- prep kernels ----------------

__global__ void detect_i64_kernel(const int* __restrict__ src, int* __restrict__ flag) {
  if (threadIdx.x == 0 && blockIdx.x == 0) {
    int o = 0;
    for (int i = 1; i < 32; i += 2) o |= src[i];
    *flag = (o == 0) ? 1 : 0;
  }
}

__global__ void cvt_bf16_kernel(const float* __restrict__ in, u16* __restrict__ out, size_t n4) {
  size_t i = (size_t)blockIdx.x * blockDim.x + threadIdx.x;
  if (i >= n4) return;
  float4 v = reinterpret_cast<const float4*>(in)[i];
  u16x4 o;
  o.x = f2bf(v.x); o.y = f2bf(v.y); o.z = f2bf(v.z); o.w = f2bf(v.w);
  reinterpret_cast<u16x4*>(out)[i] = o;
}

// in: [K][N] fp32 row-major  ->  out: [N][K] bf16 row-major
__global__ void transpose_cvt_kernel(const float* __restrict__ in, u16* __restrict__ out,
                                     int K, int N) {
  __shared__ float tile[32][33];
  int n0 = blockIdx.x * 32, k0 = blockIdx.y * 32;
  int tx = threadIdx.x, ty = threadIdx.y;
  #pragma unroll
  for (int i = ty; i < 32; i += 8)
    tile[i][tx] = in[(size_t)(k0 + i) * N + (n0 + tx)];
  __syncthreads();
  #pragma unroll
  for (int i = ty; i < 32; i += 8)
    out[(size_t)(n0 + i) * K + (k0 + tx)] = f2bf(tile[tx][i]);
}

// ---------------- GEMM: 256x256 tile, BK=64, 8 waves, 8-phase pipeline ----------------
// LDS layout (elems): ldsA[2][256][64] at 0, ldsB[2][256][64] at 2*BUFE.
// Swizzle (T2): storage k-group = logical k-group XOR (row&7)  (8-elem groups).
//   - write side: global_load_lds dest is linear; per-lane GLOBAL src k pre-XORed.
//   - read side : fragment k-offset XORed the same way. Involution => bijective.
// Schedule (T3/T4): per tile u (4 phases), stages: ph0 -> A1,A3 of u+1 (other buf);
//   ph1 -> B0,B1 of u+2; ph2 -> B2,B3 of u+2; ph3 -> A0,A2 of u+2 (same buf —
//   those rows' last reads completed >=2 phases earlier). Boundary wait vmcnt(6):
//   6 newest outstanding chunks belong to tile u+2; tile u+1 fully landed.
// T5: setprio(1) around each 16-MFMA cluster.

#define PHASE_MFMA(i0, i1)                                                              \
  do {                                                                                  \
    _Pragma("unroll")                                                                   \
    for (int j = 0; j < 4; ++j) {                                                       \
      acc[i0][j] = __builtin_amdgcn_mfma_f32_16x16x32_bf16(afA[0], bfr[j][0], acc[i0][j], 0, 0, 0); \
      acc[i0][j] = __builtin_amdgcn_mfma_f32_16x16x32_bf16(afA[1], bfr[j][1], acc[i0][j], 0, 0, 0); \
    }                                                                                   \
    _Pragma("unroll")                                                                   \
    for (int j = 0; j < 4; ++j) {                                                       \
      acc[i1][j] = __builtin_amdgcn_mfma_f32_16x16x32_bf16(afB[0], bfr[j][0], acc[i1][j], 0, 0, 0); \
      acc[i1][j] = __builtin_amdgcn_mfma_f32_16x16x32_bf16(afB[1], bfr[j][1], acc[i1][j], 0, 0, 0); \
    }                                                                                   \
  } while (0)

#define LDA(dst, i, ks) \
  dst = *reinterpret_cast<const bf16x8*>(As_c + arow + (i) * 16 * BK + ((ks) ? kb1 : kb0))
#define LDB(j, ks) \
  bfr[j][ks] = *reinterpret_cast<const bf16x8*>(Bs_c + brow + (j) * 16 * BK + ((ks) ? kb1 : kb0))

template <bool FIRST>
__launch_bounds__(512, 2)
__global__ void gemm_kernel(const u16* __restrict__ Abf,
                            const int* __restrict__ src,
                            const int* __restrict__ dst,
                            const int* __restrict__ is64p,
                            const u16* __restrict__ Bt,
                            const float* __restrict__ bias,
                            u16* __restrict__ hout,
                            float* __restrict__ fout,
                            const int K) {
  extern __shared__ __align__(16) u16 lds[];
  u16* const ldsA = lds;
  u16* const ldsB = lds + 2 * BUFE;

  const int t = threadIdx.x;
  const int lane = t & 63;
  const int wave = t >> 6;

  // bijective XCD swizzle: nwg = 1024 (%8==0), q = 128; nTile fastest so the
  // 4 blocks sharing an A-panel sit consecutively on one XCD.
  const int b = blockIdx.x;
  const int wgid = (b & 7) * 128 + (b >> 3);
  const int bm = (wgid >> 2) * BM;
  const int bn = (wgid & 3) * BM;

  const int wm = (wave >> 2) * 128;   // 2 waves in M
  const int wn = (wave & 3) * 64;     // 4 waves in N

  // ---- staging setup: chunk = 64 rows x 64 k (8 KiB), 1 gll16 / wave / chunk ----
  const int srow = t >> 3;                               // row within chunk (0..63)
  const int kswz = (((t & 7) ^ (srow & 7)) << 3);        // pre-swizzled k (elems)
  const int stoff = wave * 512;                          // elems: wave slice of chunk

  const u16* ap[4];   // A chunk-row base (src half for FIRST)
  const u16* ad[4];   // A dst half (FIRST only)
  const u16* bp[4];
  if constexpr (FIRST) {
    const int is64 = *is64p;
    #pragma unroll
    for (int q = 0; q < 4; ++q) {
      const int e = bm + q * 64 + srow;
      const int s = is64 ? src[2 * e] : src[e];
      const int d = is64 ? dst[2 * e] : dst[e];
      ap[q] = Abf + (size_t)s * D_NODE + kswz;
      ad[q] = Abf + (size_t)d * D_NODE + kswz;
    }
  } else {
    #pragma unroll
    for (int q = 0; q < 4; ++q) {
      ap[q] = Abf + (size_t)(bm + q * 64 + srow) * K + kswz;
      ad[q] = nullptr;
    }
  }
  #pragma unroll
  for (int q = 0; q < 4; ++q)
    bp[q] = Bt + (size_t)(bn + q * 64 + srow) * K + kswz;

  auto stageA = [&](int buf, int q, int u) {
    const u16* g;
    if constexpr (FIRST) {
      g = (u < (D_NODE / BK)) ? (ap[q] + u * BK) : (ad[q] + (u - D_NODE / BK) * BK);
    } else {
      g = ap[q] + u * BK;
    }
    gll16(g, ldsA + buf * BUFE + q * 4096 + stoff);
  };
  auto stageB = [&](int buf, int q, int u) {
    gll16(bp[q] + u * BK, ldsB + buf * BUFE + q * 4096 + stoff);
  };

  // ---- fragment read setup ----
  const int lm = lane & 15;
  const int kq8 = ((lane >> 4) & 3) << 3;          // 0,8,16,24
  const int swzr = (lm & 7) << 3;                  // row&7 XOR term (elems)
  const int kb0 = kq8 ^ swzr;                      // ks=0 storage offset
  const int kb1 = (32 + kq8) ^ swzr;               // ks=1 storage offset
  const int arow = (wm + lm) * BK;
  const int brow = (wn + lm) * BK;

  f32x4 acc[8][4] = {};

  const int NT = K / BK;

  // ---- prologue: tile0 fully (8 chunks), tile1 partially (6 chunks) ----
  #pragma unroll
  for (int q = 0; q < 4; ++q) stageB(0, q, 0);
  #pragma unroll
  for (int q = 0; q < 4; ++q) stageA(0, q, 0);
  #pragma unroll
  for (int q = 0; q < 4; ++q) stageB(1, q, 1);
  stageA(1, 0, 1);
  stageA(1, 2, 1);
  asm volatile("s_waitcnt vmcnt(6)" ::: "memory");   // tile0 landed; tile1's 6 in flight
  __builtin_amdgcn_s_barrier();

  // ---- main loop ----
  for (int u = 0; u < NT; ++u) {
    const int cb = u & 1;
    const u16* As_c = ldsA + cb * BUFE;
    const u16* Bs_c = ldsB + cb * BUFE;

    bf16x8 bfr[4][2];
    bf16x8 afA[2], afB[2];

    // ===== phase 0: all B frags + A i=0,1 (12 ds_read) | stage A1,A3 of u+1 =====
    #pragma unroll
    for (int j = 0; j < 4; ++j) { LDB(j, 0); LDB(j, 1); }
    LDA(afA[0], 0, 0); LDA(afA[1], 0, 1);
    LDA(afB[0], 1, 0); LDA(afB[1], 1, 1);
    if (u + 1 < NT) { stageA(cb ^ 1, 1, u + 1); stageA(cb ^ 1, 3, u + 1); }
    __builtin_amdgcn_s_barrier();
    asm volatile("s_waitcnt lgkmcnt(0)");
    __builtin_amdgcn_s_setprio(1);
    PHASE_MFMA(0, 1);
    __builtin_amdgcn_s_setprio(0);
    __builtin_amdgcn_s_barrier();

    // ===== phase 1: A i=2,3 | stage B0,B1 of u+2 =====
    LDA(afA[0], 2, 0); LDA(afA[1], 2, 1);
    LDA(afB[0], 3, 0); LDA(afB[1], 3, 1);
    if (u + 2 < NT) { stageB(cb, 0, u + 2); stageB(cb, 1, u + 2); }
    __builtin_amdgcn_s_barrier();
    asm volatile("s_waitcnt lgkmcnt(0)");
    __builtin_amdgcn_s_setprio(1);
    PHASE_MFMA(2, 3);
    __builtin_amdgcn_s_setprio(0);
    __builtin_amdgcn_s_barrier();

    // ===== phase 2: A i=4,5 | stage B2,B3 of u+2 =====
    LDA(afA[0], 4, 0); LDA(afA[1], 4, 1);
    LDA(afB[0], 5, 0); LDA(afB[1], 5, 1);
    if (u + 2 < NT) { stageB(cb, 2, u + 2); stageB(cb, 3, u + 2); }
    __builtin_amdgcn_s_barrier();
    asm volatile("s_waitcnt lgkmcnt(0)");
    __builtin_amdgcn_s_setprio(1);
    PHASE_MFMA(4, 5);
    __builtin_amdgcn_s_setprio(0);
    __builtin_amdgcn_s_barrier();

    // ===== phase 3: A i=6,7 | stage A0,A2 of u+2 | boundary vmcnt =====
    LDA(afA[0], 6, 0); LDA(afA[1], 6, 1);
    LDA(afB[0], 7, 0); LDA(afB[1], 7, 1);
    if (u + 2 < NT) { stageA(cb, 0, u + 2); stageA(cb, 2, u + 2); }
    __builtin_amdgcn_s_barrier();
    asm volatile("s_waitcnt lgkmcnt(0)");
    __builtin_amdgcn_s_setprio(1);
    PHASE_MFMA(6, 7);
    __builtin_amdgcn_s_setprio(0);
    if (u + 2 < NT)      asm volatile("s_waitcnt vmcnt(6)" ::: "memory");
    else if (u + 1 < NT) asm volatile("s_waitcnt vmcnt(0)" ::: "memory");
    __builtin_amdgcn_s_barrier();
  }

  // ---- epilogue: C/D layout col = lane&15, row = (lane>>4)*4 + rr ----
  const int rq = ((lane >> 4) & 3) * 4;
  #pragma unroll
  for (int j = 0; j < 4; ++j) {
    const int n = bn + wn + 16 * j + lm;
    const float bj = bias[n];
    #pragma unroll
    for (int i = 0; i < 8; ++i) {
      const int m0 = bm + wm + 16 * i + rq;
      f32x4 c = acc[i][j];
      #pragma unroll
      for (int rr = 0; rr < 4; ++rr) {
        float v = c[rr] + bj;
        if (FIRST) {
          v = fmaxf(v, 0.0f);
          hout[(size_t)(m0 + rr) * D_HID + n] = f2bf(v);
        } else {
          fout[(size_t)(m0 + rr) * D_HID + n] = v;
        }
      }
    }
  }
}

// ---------------- launch ----------------

extern "C" void kernel_launch(void* const* d_in, const int* in_sizes, int n_in,
                              void* d_out, int out_size, void* d_ws, size_t ws_size,
                              hipStream_t stream) {
  const float* node_feats = (const float*)d_in[0];
  const int*   src        = (const int*)d_in[1];
  const int*   dst        = (const int*)d_in[2];
  const float* W1         = (const float*)d_in[3];
  const float* b1         = (const float*)d_in[4];
  const float* W2         = (const float*)d_in[5];
  const float* b2         = (const float*)d_in[6];
  float* out = (float*)d_out;

  // workspace layout (bf16 elements)
  u16* ws = (u16*)d_ws;
  const size_t NODE_E = (size_t)N_NODES * D_NODE;       // 51,200,000
  u16* node_bf = ws;
  u16* W1T = node_bf + NODE_E;                          // [1024][2048]
  u16* W2T = W1T + (size_t)2048 * 1024;                 // [1024][1024]
  u16* h   = W2T + (size_t)1024 * 1024;                 // [65536][1024]
  int* flag = (int*)(h + (size_t)N_EDGES * D_HID);

  static bool attr_set = false;
  if (!attr_set) {
    hipFuncSetAttribute(reinterpret_cast<const void*>(&gemm_kernel<true>),
                        hipFuncAttributeMaxDynamicSharedMemorySize, LDS_BYTES);
    hipFuncSetAttribute(reinterpret_cast<const void*>(&gemm_kernel<false>),
                        hipFuncAttributeMaxDynamicSharedMemorySize, LDS_BYTES);
    attr_set = true;
  }

  detect_i64_kernel<<<1, 64, 0, stream>>>(src, flag);

  cvt_bf16_kernel<<<(unsigned)(NODE_E / 4 / 256), 256, 0, stream>>>(node_feats, node_bf, NODE_E / 4);

  transpose_cvt_kernel<<<dim3(1024 / 32, 2048 / 32), dim3(32, 8), 0, stream>>>(W1, W1T, 2048, 1024);
  transpose_cvt_kernel<<<dim3(1024 / 32, 1024 / 32), dim3(32, 8), 0, stream>>>(W2, W2T, 1024, 1024);

  // GEMM1: [65536 x 2048] gathered @ W1T -> relu -> h (bf16)
  gemm_kernel<true><<<1024, 512, LDS_BYTES, stream>>>(
      node_bf, src, dst, flag, W1T, b1, h, nullptr, 2 * D_NODE);

  // GEMM2: h @ W2T + b2 -> out (fp32)
  gemm_kernel<false><<<1024, 512, LDS_BYTES, stream>>>(
      h, nullptr, nullptr, nullptr, W2T, b2, nullptr, out, D_HID);
}

// Round 4
// 804.836 us; speedup vs baseline: 1.0213x; 1.0213x over previous
//
#include <hip/hip_runtime.h>
#include <stdint.h>
#include <stddef.h>

typedef unsigned short u16;
typedef __bf16 bf16_t;
typedef bf16_t bf16x8 __attribute__((ext_vector_type(8)));
typedef float f32x4 __attribute__((ext_vector_type(4)));
typedef u16 u16x4 __attribute__((ext_vector_type(4)));

#define N_NODES 50000
#define N_EDGES 65536
#define D_NODE 1024
#define D_HID 1024

// GEMM geometry: 256x256 tile, BK=64, 8 waves, 128 KiB LDS, 1 block/CU
#define BM 256
#define BK 64
#define BUFE (BM * BK)                 // 16384 elems = 32 KiB per (A or B) buffer
#define LDS_BYTES (4 * BUFE * 2)       // 2 dbuf x (A+B) x 2B = 131072 B

// ---------------- helpers ----------------

__device__ __forceinline__ u16 f2bf(float f) {
  union { float f; uint32_t u; } v; v.f = f;
  uint32_t u = v.u;
  u += 0x7FFF + ((u >> 16) & 1);   // RNE
  return (u16)(u >> 16);
}

typedef __attribute__((address_space(1))) const void GV;
typedef __attribute__((address_space(3))) void LV;

// async global->LDS, 16B per lane; LDS dest = wave-uniform base + lane*16
__device__ __forceinline__ void gll16(const void* g, void* lds_wave_base) {
  __builtin_amdgcn_global_load_lds((GV*)g, (LV*)lds_wave_base, 16, 0, 0);
}

// ---------------- prep kernels ----------------

__global__ void detect_i64_kernel(const int* __restrict__ src, int* __restrict__ flag) {
  if (threadIdx.x == 0 && blockIdx.x == 0) {
    int o = 0;
    for (int i = 1; i < 32; i += 2) o |= src[i];
    *flag = (o == 0) ? 1 : 0;
  }
}

__global__ void cvt_bf16_kernel(const float* __restrict__ in, u16* __restrict__ out, size_t n4) {
  size_t i = (size_t)blockIdx.x * blockDim.x + threadIdx.x;
  if (i >= n4) return;
  float4 v = reinterpret_cast<const float4*>(in)[i];
  u16x4 o;
  o.x = f2bf(v.x); o.y = f2bf(v.y); o.z = f2bf(v.z); o.w = f2bf(v.w);
  reinterpret_cast<u16x4*>(out)[i] = o;
}

// in: [K][N] fp32 row-major  ->  out: [N][K] bf16 row-major
__global__ void transpose_cvt_kernel(const float* __restrict__ in, u16* __restrict__ out,
                                     int K, int N) {
  __shared__ float tile[32][33];
  int n0 = blockIdx.x * 32, k0 = blockIdx.y * 32;
  int tx = threadIdx.x, ty = threadIdx.y;
  #pragma unroll
  for (int i = ty; i < 32; i += 8)
    tile[i][tx] = in[(size_t)(k0 + i) * N + (n0 + tx)];
  __syncthreads();
  #pragma unroll
  for (int i = ty; i < 32; i += 8)
    out[(size_t)(n0 + i) * K + (k0 + tx)] = f2bf(tile[tx][i]);
}

// ---------------- GEMM body ----------------
// 256x256 tile, BK=64, 8 waves (2M x 4N), per-wave 128x64 C via 8x4x2 mfma 16x16x32.
// LDS swizzle (T2, measured 0-conflict in r2): storage k-group = logical ^ (row&7);
//   write side pre-permutes the GLOBAL source k (LDS dest linear, rule #21);
//   read side XORs the fragment k-offset identically.
// Schedule (NEW): ONE barrier + ONE vmcnt(0) per K-tile; reads hit buffer cb,
//   stage-writes hit cb^1 (depth-1 prefetch) -> no intra-tile LDS conflicts.
//   Quadrant pipeline: issue reads of quadrant q+1 BEFORE the MFMAs of quadrant q;
//   the compiler's counted lgkmcnt overlaps LDS latency under the matrix pipe
//   (round-2's explicit lgkmcnt(0)-per-phase serialized read and MFMA epochs —
//   2000 + 2483 cyc/tile; overlapped target ~3000).
// Boundary safety: each wave's MFMAs dep-wait all its reads before it reaches the
//   barrier -> post-barrier stage-issues into cb are WAR-safe; vmcnt(0)+barrier
//   ensures the cooperatively-staged next tile landed before its first read.

template <bool FIRST>
__device__ __forceinline__ void gemm_body(const u16* __restrict__ Abf,
                                          const int* __restrict__ src,
                                          const int* __restrict__ dst,
                                          const int* __restrict__ is64p,
                                          const u16* __restrict__ Bt,
                                          const float* __restrict__ bias,
                                          u16* __restrict__ hout,
                                          float* __restrict__ fout,
                                          const int K) {
  extern __shared__ __align__(16) u16 lds[];
  u16* const ldsA = lds;                 // [2][BUFE]
  u16* const ldsB = lds + 2 * BUFE;      // [2][BUFE]

  const int t = threadIdx.x;
  const int lane = t & 63;
  const int wave = t >> 6;

  // bijective XCD swizzle: nwg = 1024 (%8==0); nTile fastest so the 4 blocks
  // sharing an A-panel sit consecutively on one XCD.
  const int b = blockIdx.x;
  const int wgid = (b & 7) * 128 + (b >> 3);
  const int bm = (wgid >> 2) * BM;
  const int bn = (wgid & 3) * BM;

  const int wm = (wave >> 2) * 128;   // 2 waves in M
  const int wn = (wave & 3) * 64;     // 4 waves in N

  // ---- staging setup: chunk = 64 rows x 64 k (8 KiB), 1 gll16 / wave / chunk ----
  const int srow = t >> 3;                               // row within chunk (0..63)
  const int kswz = (((t & 7) ^ (srow & 7)) << 3);        // pre-swizzled k (elems)
  const int stoff = wave * 512;                          // wave slice of chunk

  const u16* ap[4];   // A chunk-row base (src half for FIRST)
  const u16* ad[4];   // A dst half (FIRST only)
  const u16* bp[4];
  if constexpr (FIRST) {
    const int is64 = *is64p;
    #pragma unroll
    for (int q = 0; q < 4; ++q) {
      const int e = bm + q * 64 + srow;
      const int s = is64 ? src[2 * e] : src[e];
      const int d = is64 ? dst[2 * e] : dst[e];
      ap[q] = Abf + (size_t)s * D_NODE + kswz;
      ad[q] = Abf + (size_t)d * D_NODE + kswz;
    }
  } else {
    #pragma unroll
    for (int q = 0; q < 4; ++q) {
      ap[q] = Abf + (size_t)(bm + q * 64 + srow) * K + kswz;
      ad[q] = nullptr;
    }
  }
  #pragma unroll
  for (int q = 0; q < 4; ++q)
    bp[q] = Bt + (size_t)(bn + q * 64 + srow) * K + kswz;

  auto stageA = [&](int buf, int q, int u) {
    const u16* g;
    if constexpr (FIRST) {
      g = (u < (D_NODE / BK)) ? (ap[q] + u * BK) : (ad[q] + (u - D_NODE / BK) * BK);
    } else {
      g = ap[q] + u * BK;
    }
    gll16(g, ldsA + buf * BUFE + q * 4096 + stoff);
  };
  auto stageB = [&](int buf, int q, int u) {
    gll16(bp[q] + u * BK, ldsB + buf * BUFE + q * 4096 + stoff);
  };

  // ---- fragment read setup (round-2 measured-correct formulas) ----
  const int lm = lane & 15;
  const int kq8 = ((lane >> 4) & 3) << 3;          // 0,8,16,24
  const int swzr = (lm & 7) << 3;                  // row&7 XOR term (elems)
  const int kb0 = kq8 ^ swzr;                      // ks=0 storage offset
  const int kb1 = (32 + kq8) ^ swzr;               // ks=1 storage offset
  const int arow = (wm + lm) * BK;
  const int brow = (wn + lm) * BK;

  f32x4 acc[8][4] = {};

  const int NT = K / BK;

  // ---- prologue: stage tile0 into buf0, drain, barrier ----
  #pragma unroll
  for (int q = 0; q < 4; ++q) stageA(0, q, 0);
  #pragma unroll
  for (int q = 0; q < 4; ++q) stageB(0, q, 0);
  asm volatile("s_waitcnt vmcnt(0)" ::: "memory");
  __builtin_amdgcn_s_barrier();

  // ---- main loop: 1 barrier + 1 vmcnt per K-tile, pipelined quadrants ----
  for (int u = 0; u < NT; ++u) {
    const int cb = u & 1;
    const u16* As_c = ldsA + cb * BUFE;
    const u16* Bs_c = ldsB + cb * BUFE;

    // stage tile u+1 into the OTHER buffer (no conflict with this tile's reads)
    if (u + 1 < NT) {
      const int nb = cb ^ 1;
      stageA(nb, 0, u + 1); stageA(nb, 1, u + 1);
      stageA(nb, 2, u + 1); stageA(nb, 3, u + 1);
      stageB(nb, 0, u + 1); stageB(nb, 1, u + 1);
      stageB(nb, 2, u + 1); stageB(nb, 3, u + 1);
    }

    bf16x8 aq[4], ar[4], bq[4], br[4];

    // Q0 reads: B ks0 + A ks0 i0-3
    #pragma unroll
    for (int j = 0; j < 4; ++j)
      bq[j] = *reinterpret_cast<const bf16x8*>(Bs_c + brow + j * 1024 + kb0);
    #pragma unroll
    for (int i = 0; i < 4; ++i)
      aq[i] = *reinterpret_cast<const bf16x8*>(As_c + arow + i * 1024 + kb0);
    // Q1 reads: A ks0 i4-7
    #pragma unroll
    for (int i = 0; i < 4; ++i)
      ar[i] = *reinterpret_cast<const bf16x8*>(As_c + arow + (i + 4) * 1024 + kb0);

    // MFMA Q0 (compiler inserts counted lgkm waits; Q1 reads stay in flight)
    __builtin_amdgcn_s_setprio(1);
    #pragma unroll
    for (int i = 0; i < 4; ++i)
      #pragma unroll
      for (int j = 0; j < 4; ++j)
        acc[i][j] = __builtin_amdgcn_mfma_f32_16x16x32_bf16(aq[i], bq[j], acc[i][j], 0, 0, 0);
    __builtin_amdgcn_s_setprio(0);

    // Q2 reads: B ks1 + A ks1 i0-3 (reuse aq)
    #pragma unroll
    for (int j = 0; j < 4; ++j)
      br[j] = *reinterpret_cast<const bf16x8*>(Bs_c + brow + j * 1024 + kb1);
    #pragma unroll
    for (int i = 0; i < 4; ++i)
      aq[i] = *reinterpret_cast<const bf16x8*>(As_c + arow + i * 1024 + kb1);

    // MFMA Q1: ks0 i4-7
    __builtin_amdgcn_s_setprio(1);
    #pragma unroll
    for (int i = 0; i < 4; ++i)
      #pragma unroll
      for (int j = 0; j < 4; ++j)
        acc[i + 4][j] = __builtin_amdgcn_mfma_f32_16x16x32_bf16(ar[i], bq[j], acc[i + 4][j], 0, 0, 0);
    __builtin_amdgcn_s_setprio(0);

    // Q3 reads: A ks1 i4-7 (reuse ar)
    #pragma unroll
    for (int i = 0; i < 4; ++i)
      ar[i] = *reinterpret_cast<const bf16x8*>(As_c + arow + (i + 4) * 1024 + kb1);

    // MFMA Q2: ks1 i0-3
    __builtin_amdgcn_s_setprio(1);
    #pragma unroll
    for (int i = 0; i < 4; ++i)
      #pragma unroll
      for (int j = 0; j < 4; ++j)
        acc[i][j] = __builtin_amdgcn_mfma_f32_16x16x32_bf16(aq[i], br[j], acc[i][j], 0, 0, 0);
    // MFMA Q3: ks1 i4-7
    #pragma unroll
    for (int i = 0; i < 4; ++i)
      #pragma unroll
      for (int j = 0; j < 4; ++j)
        acc[i + 4][j] = __builtin_amdgcn_mfma_f32_16x16x32_bf16(ar[i], br[j], acc[i + 4][j], 0, 0, 0);
    __builtin_amdgcn_s_setprio(0);

    // tile boundary: next tile's staged chunks must have landed (all waves),
    // and this wave's reads are already complete (MFMA dep-waits above).
    asm volatile("s_waitcnt vmcnt(0)" ::: "memory");
    __builtin_amdgcn_s_barrier();
  }

  // ---- epilogue: C/D layout col = lane&15, row = (lane>>4)*4 + rr ----
  const int rq = ((lane >> 4) & 3) * 4;
  #pragma unroll
  for (int j = 0; j < 4; ++j) {
    const int n = bn + wn + 16 * j + lm;
    const float bj = bias[n];
    #pragma unroll
    for (int i = 0; i < 8; ++i) {
      const int m0 = bm + wm + 16 * i + rq;
      f32x4 c = acc[i][j];
      #pragma unroll
      for (int rr = 0; rr < 4; ++rr) {
        float vv = c[rr] + bj;
        if (FIRST) {
          vv = fmaxf(vv, 0.0f);
          hout[(size_t)(m0 + rr) * D_HID + n] = f2bf(vv);
        } else {
          fout[(size_t)(m0 + rr) * D_HID + n] = vv;
        }
      }
    }
  }
}

__launch_bounds__(512, 2)
__global__ void gemm1_kernel(const u16* __restrict__ Abf, const int* __restrict__ src,
                             const int* __restrict__ dst, const int* __restrict__ is64p,
                             const u16* __restrict__ Bt, const float* __restrict__ bias,
                             u16* __restrict__ hout) {
  gemm_body<true>(Abf, src, dst, is64p, Bt, bias, hout, nullptr, 2 * D_NODE);
}

__launch_bounds__(512, 2)
__global__ void gemm2_kernel(const u16* __restrict__ Abf, const u16* __restrict__ Bt,
                             const float* __restrict__ bias, float* __restrict__ fout) {
  gemm_body<false>(Abf, nullptr, nullptr, nullptr, Bt, bias, nullptr, fout, D_HID);
}

// ---------------- launch ----------------

extern "C" void kernel_launch(void* const* d_in, const int* in_sizes, int n_in,
                              void* d_out, int out_size, void* d_ws, size_t ws_size,
                              hipStream_t stream) {
  const float* node_feats = (const float*)d_in[0];
  const int*   src        = (const int*)d_in[1];
  const int*   dst        = (const int*)d_in[2];
  const float* W1         = (const float*)d_in[3];
  const float* b1         = (const float*)d_in[4];
  const float* W2         = (const float*)d_in[5];
  const float* b2         = (const float*)d_in[6];
  float* out = (float*)d_out;

  // workspace layout (bf16 elements)
  u16* ws = (u16*)d_ws;
  const size_t NODE_E = (size_t)N_NODES * D_NODE;       // 51,200,000
  u16* node_bf = ws;
  u16* W1T = node_bf + NODE_E;                          // [1024][2048]
  u16* W2T = W1T + (size_t)2048 * 1024;                 // [1024][1024]
  u16* h   = W2T + (size_t)1024 * 1024;                 // [65536][1024]
  int* flag = (int*)(h + (size_t)N_EDGES * D_HID);

  static bool attr_set = false;
  if (!attr_set) {
    hipFuncSetAttribute(reinterpret_cast<const void*>(&gemm1_kernel),
                        hipFuncAttributeMaxDynamicSharedMemorySize, LDS_BYTES);
    hipFuncSetAttribute(reinterpret_cast<const void*>(&gemm2_kernel),
                        hipFuncAttributeMaxDynamicSharedMemorySize, LDS_BYTES);
    attr_set = true;
  }

  detect_i64_kernel<<<1, 64, 0, stream>>>(src, flag);

  cvt_bf16_kernel<<<(unsigned)(NODE_E / 4 / 256), 256, 0, stream>>>(node_feats, node_bf, NODE_E / 4);

  transpose_cvt_kernel<<<dim3(1024 / 32, 2048 / 32), dim3(32, 8), 0, stream>>>(W1, W1T, 2048, 1024);
  transpose_cvt_kernel<<<dim3(1024 / 32, 1024 / 32), dim3(32, 8), 0, stream>>>(W2, W2T, 1024, 1024);

  // GEMM1: [65536 x 2048] gathered @ W1T -> relu -> h (bf16)
  gemm1_kernel<<<1024, 512, LDS_BYTES, stream>>>(node_bf, src, dst, flag, W1T, b1, h);

  // GEMM2: h @ W2T + b2 -> out (fp32)
  gemm2_kernel<<<1024, 512, LDS_BYTES, stream>>>(h, W2T, b2, out);
}

// Round 5
// 804.484 us; speedup vs baseline: 1.0217x; 1.0004x over previous
//
#include <hip/hip_runtime.h>
#include <stdint.h>
#include <stddef.h>

typedef unsigned short u16;
typedef __bf16 bf16_t;
typedef bf16_t bf16x8 __attribute__((ext_vector_type(8)));
typedef float f32x4 __attribute__((ext_vector_type(4)));
typedef u16 u16x4 __attribute__((ext_vector_type(4)));

#define N_NODES 50000
#define N_EDGES 65536
#define D_NODE 1024
#define D_HID 1024

// GEMM geometry: 256x256 tile, BK=64, 8 waves, 128 KiB LDS, 1 block/CU
#define BM 256
#define BK 64
#define BUFE (BM * BK)                 // 16384 elems = 32 KiB per (A or B) buffer
#define LDS_BYTES (4 * BUFE * 2)       // 2 dbuf x (A+B) x 2B = 131072 B

// ---------------- helpers ----------------

__device__ __forceinline__ u16 f2bf(float f) {
  union { float f; uint32_t u; } v; v.f = f;
  uint32_t u = v.u;
  u += 0x7FFF + ((u >> 16) & 1);   // RNE
  return (u16)(u >> 16);
}

typedef __attribute__((address_space(1))) const void GV;
typedef __attribute__((address_space(3))) void LV;

// async global->LDS, 16B per lane; LDS dest = wave-uniform base + lane*16
__device__ __forceinline__ void gll16(const void* g, void* lds_wave_base) {
  __builtin_amdgcn_global_load_lds((GV*)g, (LV*)lds_wave_base, 16, 0, 0);
}

// ---------------- prep kernels ----------------

__global__ void detect_i64_kernel(const int* __restrict__ src, int* __restrict__ flag) {
  if (threadIdx.x == 0 && blockIdx.x == 0) {
    int o = 0;
    for (int i = 1; i < 32; i += 2) o |= src[i];
    *flag = (o == 0) ? 1 : 0;
  }
}

__global__ void cvt_bf16_kernel(const float* __restrict__ in, u16* __restrict__ out, size_t n4) {
  size_t i = (size_t)blockIdx.x * blockDim.x + threadIdx.x;
  if (i >= n4) return;
  float4 v = reinterpret_cast<const float4*>(in)[i];
  u16x4 o;
  o.x = f2bf(v.x); o.y = f2bf(v.y); o.z = f2bf(v.z); o.w = f2bf(v.w);
  reinterpret_cast<u16x4*>(out)[i] = o;
}

// in: [K][N] fp32 row-major  ->  out: [N][K] bf16 row-major
__global__ void transpose_cvt_kernel(const float* __restrict__ in, u16* __restrict__ out,
                                     int K, int N) {
  __shared__ float tile[32][33];
  int n0 = blockIdx.x * 32, k0 = blockIdx.y * 32;
  int tx = threadIdx.x, ty = threadIdx.y;
  #pragma unroll
  for (int i = ty; i < 32; i += 8)
    tile[i][tx] = in[(size_t)(k0 + i) * N + (n0 + tx)];
  __syncthreads();
  #pragma unroll
  for (int i = ty; i < 32; i += 8)
    out[(size_t)(n0 + i) * K + (k0 + tx)] = f2bf(tile[tx][i]);
}

// ---------------- GEMM body ----------------
// 256x256 tile, BK=64, 8 waves (2M x 4N), per-wave 128x64 C via 8x4x2 mfma 16x16x32.
// LDS swizzle (T2, measured 0-conflict): storage k-group = logical ^ (row&7);
//   write side pre-permutes the GLOBAL source k (LDS dest linear, rule #21);
//   read side XORs the fragment k-offset identically.
// Schedule (T3 + T4, depth-2 counted vmcnt — round-4 post-mortem fix):
//   tile u reads buf cb=u&1; tile u+1 is in flight into cb^1 (issued mid-tile u-1);
//   mid-tile u (after all 24 ds_reads drained + barrier #1) stage tile u+2 into cb
//   (WAR-safe: every wave's reads of cb completed before barrier #1).
//   Boundary wait = vmcnt(8): per-wave FIFO groups are exactly 8 gll16, so 8
//   outstanding == group u+2 only => group u+1 landed. NEVER vmcnt(0) in steady
//   state (T4, m218); cover for a group = one full tile (~3500 cyc) instead of
//   round-4's intra-tile ~2500 with forced drain.
// Quadrant pipeline within the read region: issue reads of quadrant q+1 before
//   MFMAs of quadrant q; compiler inserts counted lgkm waits (m97 asm evidence).

template <bool FIRST>
__device__ __forceinline__ void gemm_body(const u16* __restrict__ Abf,
                                          const int* __restrict__ src,
                                          const int* __restrict__ dst,
                                          const int* __restrict__ is64p,
                                          const u16* __restrict__ Bt,
                                          const float* __restrict__ bias,
                                          u16* __restrict__ hout,
                                          float* __restrict__ fout,
                                          const int K) {
  extern __shared__ __align__(16) u16 lds[];
  u16* const ldsA = lds;                 // [2][BUFE]
  u16* const ldsB = lds + 2 * BUFE;      // [2][BUFE]

  const int t = threadIdx.x;
  const int lane = t & 63;
  const int wave = t >> 6;

  // bijective XCD swizzle: nwg = 1024 (%8==0); nTile fastest so the 4 blocks
  // sharing an A-panel sit consecutively on one XCD.
  const int b = blockIdx.x;
  const int wgid = (b & 7) * 128 + (b >> 3);
  const int bm = (wgid >> 2) * BM;
  const int bn = (wgid & 3) * BM;

  const int wm = (wave >> 2) * 128;   // 2 waves in M
  const int wn = (wave & 3) * 64;     // 4 waves in N

  // ---- staging setup: chunk = 64 rows x 64 k (8 KiB), 1 gll16 / wave / chunk ----
  const int srow = t >> 3;                               // row within chunk (0..63)
  const int kswz = (((t & 7) ^ (srow & 7)) << 3);        // pre-swizzled k (elems)
  const int stoff = wave * 512;                          // wave slice of chunk

  const u16* ap[4];   // A chunk-row base (src half for FIRST)
  const u16* ad[4];   // A dst half (FIRST only)
  const u16* bp[4];
  if constexpr (FIRST) {
    const int is64 = *is64p;
    #pragma unroll
    for (int q = 0; q < 4; ++q) {
      const int e = bm + q * 64 + srow;
      const int s = is64 ? src[2 * e] : src[e];
      const int d = is64 ? dst[2 * e] : dst[e];
      ap[q] = Abf + (size_t)s * D_NODE + kswz;
      ad[q] = Abf + (size_t)d * D_NODE + kswz;
    }
  } else {
    #pragma unroll
    for (int q = 0; q < 4; ++q) {
      ap[q] = Abf + (size_t)(bm + q * 64 + srow) * K + kswz;
      ad[q] = nullptr;
    }
  }
  #pragma unroll
  for (int q = 0; q < 4; ++q)
    bp[q] = Bt + (size_t)(bn + q * 64 + srow) * K + kswz;

  auto stageA = [&](int buf, int q, int u) {
    const u16* g;
    if constexpr (FIRST) {
      g = (u < (D_NODE / BK)) ? (ap[q] + u * BK) : (ad[q] + (u - D_NODE / BK) * BK);
    } else {
      g = ap[q] + u * BK;
    }
    gll16(g, ldsA + buf * BUFE + q * 4096 + stoff);
  };
  auto stageB = [&](int buf, int q, int u) {
    gll16(bp[q] + u * BK, ldsB + buf * BUFE + q * 4096 + stoff);
  };
  // one full "group" = exactly 8 gll16 per thread (A0-3, B0-3) — vmcnt counting unit
  auto stageGroup = [&](int buf, int u) {
    stageA(buf, 0, u); stageA(buf, 1, u); stageA(buf, 2, u); stageA(buf, 3, u);
    stageB(buf, 0, u); stageB(buf, 1, u); stageB(buf, 2, u); stageB(buf, 3, u);
  };

  // ---- fragment read setup (measured-correct formulas) ----
  const int lm = lane & 15;
  const int kq8 = ((lane >> 4) & 3) << 3;          // 0,8,16,24
  const int swzr = (lm & 7) << 3;                  // row&7 XOR term (elems)
  const int kb0 = kq8 ^ swzr;                      // ks=0 storage offset
  const int kb1 = (32 + kq8) ^ swzr;               // ks=1 storage offset
  const int arow = (wm + lm) * BK;
  const int brow = (wn + lm) * BK;

  f32x4 acc[8][4] = {};

  const int NT = K / BK;

  // ---- prologue: stage tiles 0 (buf0) and 1 (buf1); wait tile0 only ----
  stageGroup(0, 0);
  stageGroup(1, 1);
  asm volatile("s_waitcnt vmcnt(8)" ::: "memory");   // tile0 landed; tile1 in flight
  __builtin_amdgcn_s_barrier();

  // ---- main loop: 2 barriers, counted vmcnt(8) boundary (T4) ----
  for (int u = 0; u < NT; ++u) {
    const int cb = u & 1;
    const u16* As_c = ldsA + cb * BUFE;
    const u16* Bs_c = ldsB + cb * BUFE;

    bf16x8 aq[4], ar[4], bq[4], br[4];

    // Q0 reads: B ks0 + A ks0 i0-3
    #pragma unroll
    for (int j = 0; j < 4; ++j)
      bq[j] = *reinterpret_cast<const bf16x8*>(Bs_c + brow + j * 1024 + kb0);
    #pragma unroll
    for (int i = 0; i < 4; ++i)
      aq[i] = *reinterpret_cast<const bf16x8*>(As_c + arow + i * 1024 + kb0);
    // Q1 reads: A ks0 i4-7
    #pragma unroll
    for (int i = 0; i < 4; ++i)
      ar[i] = *reinterpret_cast<const bf16x8*>(As_c + arow + (i + 4) * 1024 + kb0);

    // MFMA Q0 (Q1+ reads stay in flight under counted lgkm waits)
    __builtin_amdgcn_s_setprio(1);
    #pragma unroll
    for (int i = 0; i < 4; ++i)
      #pragma unroll
      for (int j = 0; j < 4; ++j)
        acc[i][j] = __builtin_amdgcn_mfma_f32_16x16x32_bf16(aq[i], bq[j], acc[i][j], 0, 0, 0);
    __builtin_amdgcn_s_setprio(0);

    // Q2 reads: B ks1 + A ks1 i0-3 (aq reused — Q0 MFMAs consumed it)
    #pragma unroll
    for (int j = 0; j < 4; ++j)
      br[j] = *reinterpret_cast<const bf16x8*>(Bs_c + brow + j * 1024 + kb1);
    bf16x8 aq2[4];
    #pragma unroll
    for (int i = 0; i < 4; ++i)
      aq2[i] = *reinterpret_cast<const bf16x8*>(As_c + arow + i * 1024 + kb1);
    // Q3 reads: A ks1 i4-7
    bf16x8 ar2[4];
    #pragma unroll
    for (int i = 0; i < 4; ++i)
      ar2[i] = *reinterpret_cast<const bf16x8*>(As_c + arow + (i + 4) * 1024 + kb1);

    // MFMA Q1: ks0 i4-7
    __builtin_amdgcn_s_setprio(1);
    #pragma unroll
    for (int i = 0; i < 4; ++i)
      #pragma unroll
      for (int j = 0; j < 4; ++j)
        acc[i + 4][j] = __builtin_amdgcn_mfma_f32_16x16x32_bf16(ar[i], bq[j], acc[i + 4][j], 0, 0, 0);
    __builtin_amdgcn_s_setprio(0);

    // all 24 ds_reads of this tile complete before any wave passes barrier #1
    asm volatile("s_waitcnt lgkmcnt(0)" ::: "memory");
    __builtin_amdgcn_sched_barrier(0);
    __builtin_amdgcn_s_barrier();            // barrier #1: cb fully read, block-wide
    __builtin_amdgcn_sched_barrier(0);

    // stage tile u+2 into cb (now WAR-safe); lands >= next tile
    if (u + 2 < NT) stageGroup(cb, u + 2);

    // MFMA Q2: ks1 i0-3 ; Q3: ks1 i4-7 (register-only — covers stage issue)
    __builtin_amdgcn_s_setprio(1);
    #pragma unroll
    for (int i = 0; i < 4; ++i)
      #pragma unroll
      for (int j = 0; j < 4; ++j)
        acc[i][j] = __builtin_amdgcn_mfma_f32_16x16x32_bf16(aq2[i], br[j], acc[i][j], 0, 0, 0);
    #pragma unroll
    for (int i = 0; i < 4; ++i)
      #pragma unroll
      for (int j = 0; j < 4; ++j)
        acc[i + 4][j] = __builtin_amdgcn_mfma_f32_16x16x32_bf16(ar2[i], br[j], acc[i + 4][j], 0, 0, 0);
    __builtin_amdgcn_s_setprio(0);

    // boundary (T4): steady state waits only until group u+1 landed (8 newest
    // outstanding = group u+2). Tail: penultimate tile must drain its successor.
    if (u + 2 < NT)      asm volatile("s_waitcnt vmcnt(8)" ::: "memory");
    else if (u + 1 < NT) asm volatile("s_waitcnt vmcnt(0)" ::: "memory");
    __builtin_amdgcn_s_barrier();            // barrier #2: next tile ready
  }

  // ---- epilogue: C/D layout col = lane&15, row = (lane>>4)*4 + rr ----
  const int rq = ((lane >> 4) & 3) * 4;
  #pragma unroll
  for (int j = 0; j < 4; ++j) {
    const int n = bn + wn + 16 * j + lm;
    const float bj = bias[n];
    #pragma unroll
    for (int i = 0; i < 8; ++i) {
      const int m0 = bm + wm + 16 * i + rq;
      f32x4 c = acc[i][j];
      #pragma unroll
      for (int rr = 0; rr < 4; ++rr) {
        float vv = c[rr] + bj;
        if (FIRST) {
          vv = fmaxf(vv, 0.0f);
          hout[(size_t)(m0 + rr) * D_HID + n] = f2bf(vv);
        } else {
          fout[(size_t)(m0 + rr) * D_HID + n] = vv;
        }
      }
    }
  }
}

__launch_bounds__(512, 2)
__global__ void gemm1_kernel(const u16* __restrict__ Abf, const int* __restrict__ src,
                             const int* __restrict__ dst, const int* __restrict__ is64p,
                             const u16* __restrict__ Bt, const float* __restrict__ bias,
                             u16* __restrict__ hout) {
  gemm_body<true>(Abf, src, dst, is64p, Bt, bias, hout, nullptr, 2 * D_NODE);
}

__launch_bounds__(512, 2)
__global__ void gemm2_kernel(const u16* __restrict__ Abf, const u16* __restrict__ Bt,
                             const float* __restrict__ bias, float* __restrict__ fout) {
  gemm_body<false>(Abf, nullptr, nullptr, nullptr, Bt, bias, nullptr, fout, D_HID);
}

// ---------------- launch ----------------

extern "C" void kernel_launch(void* const* d_in, const int* in_sizes, int n_in,
                              void* d_out, int out_size, void* d_ws, size_t ws_size,
                              hipStream_t stream) {
  const float* node_feats = (const float*)d_in[0];
  const int*   src        = (const int*)d_in[1];
  const int*   dst        = (const int*)d_in[2];
  const float* W1         = (const float*)d_in[3];
  const float* b1         = (const float*)d_in[4];
  const float* W2         = (const float*)d_in[5];
  const float* b2         = (const float*)d_in[6];
  float* out = (float*)d_out;

  // workspace layout (bf16 elements)
  u16* ws = (u16*)d_ws;
  const size_t NODE_E = (size_t)N_NODES * D_NODE;       // 51,200,000
  u16* node_bf = ws;
  u16* W1T = node_bf + NODE_E;                          // [1024][2048]
  u16* W2T = W1T + (size_t)2048 * 1024;                 // [1024][1024]
  u16* h   = W2T + (size_t)1024 * 1024;                 // [65536][1024]
  int* flag = (int*)(h + (size_t)N_EDGES * D_HID);

  static bool attr_set = false;
  if (!attr_set) {
    hipFuncSetAttribute(reinterpret_cast<const void*>(&gemm1_kernel),
                        hipFuncAttributeMaxDynamicSharedMemorySize, LDS_BYTES);
    hipFuncSetAttribute(reinterpret_cast<const void*>(&gemm2_kernel),
                        hipFuncAttributeMaxDynamicSharedMemorySize, LDS_BYTES);
    attr_set = true;
  }

  detect_i64_kernel<<<1, 64, 0, stream>>>(src, flag);

  cvt_bf16_kernel<<<(unsigned)(NODE_E / 4 / 256), 256, 0, stream>>>(node_feats, node_bf, NODE_E / 4);

  transpose_cvt_kernel<<<dim3(1024 / 32, 2048 / 32), dim3(32, 8), 0, stream>>>(W1, W1T, 2048, 1024);
  transpose_cvt_kernel<<<dim3(1024 / 32, 1024 / 32), dim3(32, 8), 0, stream>>>(W2, W2T, 1024, 1024);

  // GEMM1: [65536 x 2048] gathered @ W1T -> relu -> h (bf16)
  gemm1_kernel<<<1024, 512, LDS_BYTES, stream>>>(node_bf, src, dst, flag, W1T, b1, h);

  // GEMM2: h @ W2T + b2 -> out (fp32)
  gemm2_kernel<<<1024, 512, LDS_BYTES, stream>>>(h, W2T, b2, out);
}